// Round 3
// baseline (478.534 us; speedup 1.0000x reference)
//
#include <hip/hip_runtime.h>
#include <hip/hip_bf16.h>

typedef short short8 __attribute__((ext_vector_type(8)));
typedef float floatx4 __attribute__((ext_vector_type(4)));
using bf16 = __hip_bfloat16;

static constexpr int L = 2048, H = 2048, D = 4096, NS = 16, R = 128, KC = 4;
static constexpr int CCH = 64, TCH = L / CCH;        // 64 chunks x 32 steps
static constexpr int KSP = 16, KCHUNK = 4096 / KSP;  // split-K for ssm_p
static constexpr int ZOUT = 4, KOUT = 4096 / ZOUT;   // split-K for out GEMM

__device__ __forceinline__ void g2lds16(const void* g, void* l) {
  __builtin_amdgcn_global_load_lds((const __attribute__((address_space(1))) unsigned int*)g,
                                   (__attribute__((address_space(3))) unsigned int*)l,
                                   16, 0, 0);
}

// ---------------- elementwise fp32 -> bf16 cast ----------------
__global__ void cast_f2b(const float* __restrict__ in, bf16* __restrict__ out, int n) {
  int i = blockIdx.x * 256 + threadIdx.x;
  if (i < n) out[i] = __float2bfloat16(in[i]);
}

// ------------- weight transpose+cast (fp32 [Rr,Cc] -> bf16 [Cc,Rr]) -------------
__global__ void transpose_cast(const float* __restrict__ in, bf16* __restrict__ out,
                               int Rr, int Cc) {
  __shared__ float tile[32][33];
  int c0 = blockIdx.x * 32, r0 = blockIdx.y * 32;
  int tx = threadIdx.x, ty = threadIdx.y;  // 32 x 8
#pragma unroll
  for (int i = 0; i < 32; i += 8)
    tile[ty + i][tx] = in[(size_t)(r0 + ty + i) * Cc + (c0 + tx)];
  __syncthreads();
#pragma unroll
  for (int i = 0; i < 32; i += 8)
    out[(size_t)(c0 + ty + i) * Rr + (r0 + tx)] = __float2bfloat16(tile[tx][ty + i]);
}

// ==================== 256x256 8-phase MFMA GEMM (T1+T2+T3+T4+T5) ====================
// C[M,N] = A[M,K]*Bt[N,K]^T, K multiple of 128 (NT even), M,N multiples of 256.
// MODE 2: proj split — block col selects Cb (hs) or Cb2 (gate), both bf16 [L,D].
// MODE 3: split-K bf16 partials: kbeg = blockIdx.z*K, C = Cb + blockIdx.z*L*ldc.
//
// LDS: per matrix 4 panels of [256 rows][32 k-cols] bf16 (16 KiB each) = 64 KiB;
// panel (t&1)*2 + khalf. Total 128 KiB -> 1 block/CU, 8 waves.
// st_16x32 swizzle: physical 16B chunk = logical chunk ^ (((row>>3)&1)<<1),
// applied on the global SOURCE at staging (global_load_lds writes linearly)
// and on the ds_read address at consume.
//   staging lane covers row (lane>>2) -> row bit 3 = lane bit 5;
//   read lane covers row lr=(lane&15) -> row bit 3 = lane bit 3.
//
// Wait discipline (counted vmcnt, never 0 in steady state):
//   p1-end  vmcnt(8): drains (t).kh1   — issued 6 phases earlier (t-1 p0/p1)
//   tile-end vmcnt(8): drains (t+1).kh0 — issued 6 phases earlier (t-1 p2/p3)
// Invariant: 8 loads outstanding across each tile boundary, 12 peak.
// Every wait precedes an s_barrier separating it from the consuming ds_reads
// (required: each wave stages only its own 1/8 slice of a panel).
template <int MODE>
__global__ __launch_bounds__(512, 2) void gemm256(
    const bf16* __restrict__ A, int lda,
    const bf16* __restrict__ Bt, int ldb,
    bf16* __restrict__ Cb, bf16* __restrict__ Cb2, int ldc, int K) {
  __shared__ short As[4 * 8192];
  __shared__ short Bs[4 * 8192];

  // ---- XCD-aware rectangular tile map (hw XCD = linear id % 8 heuristic) ----
  // Per-XCD rectangle rn x rm tiles (4 XCD-cols x 2 XCD-rows); bijective for
  // gx%4==0 && gy%2==0 (proj 32x8, out 8x8). Cuts unique panels/XCD ~3x.
  const int gx = gridDim.x, gy = gridDim.y;
  const int orig = blockIdx.y * gx + blockIdx.x;
  const int xcd = orig & 7;
  const int rr = orig >> 3;
  const int rn = gx >> 2, rm = gy >> 1;
  const int tn = (xcd & 3) * rn + (rr % rn);
  const int tm = (xcd >> 2) * rm + (rr / rn);
  const int n0 = tn * 256, m0 = tm * 256;
  const int kbeg = (MODE == 3) ? blockIdx.z * K : 0;
  const int NT = K >> 6;  // K-tiles of 64

  const int tid = threadIdx.x;
  const int lane = tid & 63;
  const int w = tid >> 6;
  const int wm2 = w >> 2, wn4 = w & 3;      // wave tile: 128 rows x 64 cols
  const int lr = lane & 15, kq = lane >> 4;
  // ---- read-side swizzle: row bit 3 = lane bit 3 ----
  const int swzr = ((lane >> 3) & 1) << 1;
  // ds_read offsets (shorts): row*32 + swizzled 16B chunk
  const int ardo = (wm2 * 128 + lr) * 32 + (kq ^ swzr) * 8;
  const int brdo = (wn4 * 64 + lr) * 32 + (kq ^ swzr) * 8;
  // ---- staging: per-lane row (0..127 per dwordx4 instr); row bit 3 = lane bit 5 ----
  const int srow = w * 16 + (lane >> 2);
  const int swzs = ((lane >> 5) & 1) << 1;
  const int scol = ((lane & 3) ^ swzs) * 8;

  floatx4 acc[8][4];
#pragma unroll
  for (int i = 0; i < 8; i++)
#pragma unroll
    for (int j = 0; j < 4; j++)
#pragma unroll
      for (int r = 0; r < 4; r++) acc[i][j][r] = 0.f;

  // stage one half-tile (one khalf panel): 2 x global_load_lds dwordx4
  auto stageA = [&](short* pan, int kc) {
    const bf16* g = A + (size_t)(m0 + srow) * lda + (kbeg + kc + scol);
    g2lds16(g, pan + w * 512);
    g2lds16(g + (size_t)128 * lda, pan + 4096 + w * 512);
  };
  auto stageB = [&](short* pan, int kc) {
    const bf16* g = Bt + (size_t)(n0 + srow) * ldb + (kbeg + kc + scol);
    g2lds16(g, pan + w * 512);
    g2lds16(g + (size_t)128 * ldb, pan + 4096 + w * 512);
  };

#define LDA4(pan, base)                                               \
  _Pragma("unroll") for (int ii = 0; ii < 4; ii++)                    \
      af[ii] = *(const short8*)((pan) + ardo + ((base) + ii) * 512);
#define LDB4(pan)                                                     \
  _Pragma("unroll") for (int jj = 0; jj < 4; jj++)                    \
      bfr[jj] = *(const short8*)((pan) + brdo + jj * 512);
#define MFMA4(base)                                                   \
  _Pragma("unroll") for (int ii = 0; ii < 4; ii++)                    \
      _Pragma("unroll") for (int jj = 0; jj < 4; jj++)                \
          acc[(base) + ii][jj] = __builtin_amdgcn_mfma_f32_16x16x32_bf16( \
              af[ii], bfr[jj], acc[(base) + ii][jj], 0, 0, 0);
#define PHASE_SYNC()                                                  \
  __builtin_amdgcn_s_barrier();                                       \
  asm volatile("s_waitcnt lgkmcnt(0)" ::: "memory");                  \
  __builtin_amdgcn_sched_barrier(0);
#define VMW(n)                                                        \
  __builtin_amdgcn_sched_barrier(0);                                  \
  asm volatile("s_waitcnt vmcnt(" #n ")" ::: "memory");               \
  __builtin_amdgcn_sched_barrier(0);

  // ---- prologue: halves {t0.kh0.A, t0.kh0.B, t0.kh1.A, t0.kh1.B, t1.kh0.A, t1.kh0.B}
  stageA(As + 0 * 8192, 0);
  stageB(Bs + 0 * 8192, 0);
  stageA(As + 1 * 8192, 32);
  stageB(Bs + 1 * 8192, 32);
  stageA(As + 2 * 8192, 64);
  stageB(Bs + 2 * 8192, 64);
  VMW(8);  // t0.kh0 resident (t0.kh1 + t1.kh0 stay in flight)
  __builtin_amdgcn_s_barrier();

// ---- one K-tile: 4 phases of (khalf, m-half); stages per phase:
//   p0: A.kh1(t+1)  p1: B.kh1(t+1)  p2: A.kh0(t+2)  p3: B.kh0(t+2)
#define GTILE(t, par)                                                      \
  {                                                                        \
    short* Ak0 = As + (par) * 16384;                                       \
    short* Bk0 = Bs + (par) * 16384;                                       \
    short* Ak1 = Ak0 + 8192;                                               \
    short* Bk1 = Bk0 + 8192;                                               \
    short* An1 = As + (1 - (par)) * 16384 + 8192;                          \
    short* Bn1 = Bs + (1 - (par)) * 16384 + 8192;                          \
    short8 af[4], bfr[4];                                                  \
    /* phase 0: kh0, m-frags 0..3 */                                       \
    LDA4(Ak0, 0); LDB4(Bk0);                                               \
    if ((t) + 1 < NT) stageA(An1, ((t) + 1) * 64 + 32);                    \
    PHASE_SYNC();                                                          \
    __builtin_amdgcn_s_setprio(1); MFMA4(0); __builtin_amdgcn_s_setprio(0);\
    __builtin_amdgcn_s_barrier();                                          \
    /* phase 1: kh0, m-frags 4..7 */                                       \
    LDA4(Ak0, 4);                                                          \
    if ((t) + 1 < NT) stageB(Bn1, ((t) + 1) * 64 + 32);                    \
    PHASE_SYNC();                                                          \
    __builtin_amdgcn_s_setprio(1); MFMA4(4); __builtin_amdgcn_s_setprio(0);\
    if ((t) < NT - 1) { VMW(8); } else { VMW(0); }  /* drain (t).kh1 */    \
    __builtin_amdgcn_s_barrier();                                          \
    /* phase 2: kh1, m-frags 0..3 */                                       \
    LDA4(Ak1, 0); LDB4(Bk1);                                               \
    if ((t) + 2 < NT) stageA(Ak0, ((t) + 2) * 64);                         \
    PHASE_SYNC();                                                          \
    __builtin_amdgcn_s_setprio(1); MFMA4(0); __builtin_amdgcn_s_setprio(0);\
    __builtin_amdgcn_s_barrier();                                          \
    /* phase 3: kh1, m-frags 4..7 */                                       \
    LDA4(Ak1, 4);                                                          \
    if ((t) + 2 < NT) stageB(Bk0, ((t) + 2) * 64);                         \
    PHASE_SYNC();                                                          \
    __builtin_amdgcn_s_setprio(1); MFMA4(4); __builtin_amdgcn_s_setprio(0);\
    /* drain (t+1).kh0 */                                                  \
    if ((t) < NT - 2) { VMW(8); }                                          \
    else if ((t) == NT - 2) { VMW(4); }                                    \
    else { VMW(0); }                                                       \
    __builtin_amdgcn_s_barrier();                                          \
  }

  for (int t = 0; t < NT; t += 2) {
    GTILE(t, 0);
    GTILE(t + 1, 1);
  }
#undef GTILE
#undef VMW
#undef PHASE_SYNC
#undef MFMA4
#undef LDB4
#undef LDA4

  // ---- epilogue ----
  bf16* base = Cb;
  int coff = 0, ld = ldc;
  if (MODE == 2) {
    if (n0 >= D) { base = Cb2; coff = D; }
    ld = D;
  }
  if (MODE == 3) base = Cb + (size_t)blockIdx.z * L * ldc;
  const int rb = kq * 4;  // C/D: col = lane&15, row = (lane>>4)*4 + reg
#pragma unroll
  for (int i = 0; i < 8; i++)
#pragma unroll
    for (int j = 0; j < 4; j++) {
      int col = n0 + wn4 * 64 + j * 16 + lr - coff;
      int row = m0 + wm2 * 128 + i * 16 + rb;
#pragma unroll
      for (int r = 0; r < 4; r++)
        base[(size_t)(row + r) * ld + col] = __float2bfloat16(acc[i][j][r]);
    }
}

// ------- dense bf16 MFMA GEMM (old 128x128 structure) — kept for the small dt GEMM -------
template <int MODE>
__global__ __launch_bounds__(256) void gemm_async(
    const bf16* __restrict__ A, int lda,
    const bf16* __restrict__ Bt, int ldb,
    bf16* __restrict__ Cb, bf16* __restrict__ Cb2, int ldc, int K) {
  __shared__ short As[2 * 128 * 32];
  __shared__ short Bs[2 * 128 * 32];
  const int m0 = blockIdx.y * 128, n0 = blockIdx.x * 128;
  const int kbeg = (MODE == 3) ? blockIdx.z * K : 0;
  const int tid = threadIdx.x;
  const int lane = tid & 63;
  const int wave = tid >> 6;
  const int wm = (wave >> 1) * 64, wn = (wave & 1) * 64;
  const int lr = lane & 15, kq = lane >> 4;
  const int sr = lane >> 2, sc = (lane & 3) * 8;

  const bf16* Ab = A + (size_t)(m0 + wave * 16 + sr) * lda + sc;
  const bf16* Bb = Bt + (size_t)(n0 + wave * 16 + sr) * ldb + sc;
  short* Asw = &As[wave * 16 * 32];
  short* Bsw = &Bs[wave * 16 * 32];

  floatx4 acc[4][4];
#pragma unroll
  for (int i = 0; i < 4; i++)
#pragma unroll
    for (int j = 0; j < 4; j++)
#pragma unroll
      for (int r = 0; r < 4; r++) acc[i][j][r] = 0.f;

  for (int k0 = kbeg; k0 < kbeg + K; k0 += 64) {
    __syncthreads();
#pragma unroll
    for (int h = 0; h < 2; h++) {
      int kk = k0 + h * 32;
#pragma unroll
      for (int j = 0; j < 2; j++) {
        g2lds16(Ab + (size_t)j * 64 * lda + kk, Asw + h * 4096 + j * 64 * 32);
        g2lds16(Bb + (size_t)j * 64 * ldb + kk, Bsw + h * 4096 + j * 64 * 32);
      }
    }
    __syncthreads();
#pragma unroll
    for (int h = 0; h < 2; h++) {
      short8 af[4], bfr[4];
#pragma unroll
      for (int i = 0; i < 4; i++)
        af[i] = *(const short8*)(&As[h * 4096 + (wm + i * 16 + lr) * 32 + kq * 8]);
#pragma unroll
      for (int j = 0; j < 4; j++)
        bfr[j] = *(const short8*)(&Bs[h * 4096 + (wn + j * 16 + lr) * 32 + kq * 8]);
#pragma unroll
      for (int i = 0; i < 4; i++)
#pragma unroll
        for (int j = 0; j < 4; j++)
          acc[i][j] = __builtin_amdgcn_mfma_f32_16x16x32_bf16(af[i], bfr[j], acc[i][j], 0, 0, 0);
    }
  }

  bf16* base = Cb;
  int coff = 0, ld = ldc;
  if (MODE == 2) {
    if (n0 >= D) { base = Cb2; coff = D; }
    ld = D;
  }
  if (MODE == 3) base = Cb + (size_t)blockIdx.z * L * ldc;
  const int rb = kq * 4;
#pragma unroll
  for (int i = 0; i < 4; i++)
#pragma unroll
    for (int j = 0; j < 4; j++) {
      int col = n0 + wn + j * 16 + lr - coff;
      int row = m0 + wm + i * 16 + rb;
#pragma unroll
      for (int r = 0; r < 4; r++)
        base[(size_t)(row + r) * ld + col] = __float2bfloat16(acc[i][j][r]);
    }
}

// ------- out split-K reduce: bf16 partials -> fp32, 8 elems/thread -------
__global__ void out_reduce(const unsigned short* __restrict__ P, float* __restrict__ out) {
  int i = blockIdx.x * 256 + threadIdx.x;
  const size_t LH = (size_t)L * H;
  float acc[8];
#pragma unroll
  for (int e = 0; e < 8; e++) acc[e] = 0.f;
#pragma unroll
  for (int z = 0; z < ZOUT; z++) {
    short8 v = *(const short8*)(P + z * LH + (size_t)i * 8);
#pragma unroll
    for (int e = 0; e < 8; e++)
      acc[e] += __uint_as_float(((unsigned)(unsigned short)v[e]) << 16);
  }
#pragma unroll
  for (int q = 0; q < 2; q++) {
    floatx4 o;
#pragma unroll
    for (int r = 0; r < 4; r++) o[r] = acc[q * 4 + r];
    *(floatx4*)(out + (size_t)i * 8 + q * 4) = o;
  }
}

// ------- split-K guarded GEMM for ssm_p: partial[z][M][N] over K-chunk -------
__global__ __launch_bounds__(256) void gemm_splitk(
    const bf16* __restrict__ A, int lda,
    const bf16* __restrict__ Bt, int ldb,
    float* __restrict__ P, int ldc, int N) {
  __shared__ short As[128 * 40];
  __shared__ short Bs[128 * 40];
  const int m0 = blockIdx.y * 128, n0 = blockIdx.x * 128;
  const int kbeg = blockIdx.z * KCHUNK;
  float* C = P + (size_t)blockIdx.z * L * ldc;
  const int tid = threadIdx.x;
  const int lane = tid & 63;
  const int wave = tid >> 6;
  const int wm = (wave >> 1) * 64, wn = (wave & 1) * 64;
  const int lr = lane & 15, kq = lane >> 4;
  const int srow = tid >> 2, scol = (tid & 3) * 8;

  floatx4 acc[4][4];
#pragma unroll
  for (int i = 0; i < 4; i++)
#pragma unroll
    for (int j = 0; j < 4; j++)
#pragma unroll
      for (int r = 0; r < 4; r++) acc[i][j][r] = 0.f;

  for (int k0 = kbeg; k0 < kbeg + KCHUNK; k0 += 32) {
    __syncthreads();
#pragma unroll
    for (int h = 0; h < 2; h++) {
      int r = srow + h * 64;
      short8 va = *(const short8*)((const short*)A + (size_t)(m0 + r) * lda + k0 + scol);
      *(short8*)(&As[r * 40 + scol]) = va;
    }
#pragma unroll
    for (int h = 0; h < 2; h++) {
      int r = srow + h * 64;
      short8 vb;
      if ((n0 + r) < N) {
        vb = *(const short8*)((const short*)Bt + (size_t)(n0 + r) * ldb + k0 + scol);
      } else {
#pragma unroll
        for (int q = 0; q < 8; q++) vb[q] = 0;
      }
      *(short8*)(&Bs[r * 40 + scol]) = vb;
    }
    __syncthreads();
    short8 af[4], bfr[4];
#pragma unroll
    for (int i = 0; i < 4; i++)
      af[i] = *(const short8*)(&As[(wm + i * 16 + lr) * 40 + kq * 8]);
#pragma unroll
    for (int j = 0; j < 4; j++)
      bfr[j] = *(const short8*)(&Bs[(wn + j * 16 + lr) * 40 + kq * 8]);
#pragma unroll
    for (int i = 0; i < 4; i++)
#pragma unroll
      for (int j = 0; j < 4; j++)
        acc[i][j] = __builtin_amdgcn_mfma_f32_16x16x32_bf16(af[i], bfr[j], acc[i][j], 0, 0, 0);
  }

  const int rb = kq * 4;
#pragma unroll
  for (int i = 0; i < 4; i++)
#pragma unroll
    for (int j = 0; j < 4; j++) {
      int col = n0 + wn + j * 16 + lr;
      if (col >= N) continue;
      int row = m0 + wm + i * 16 + rb;
#pragma unroll
      for (int r = 0; r < 4; r++)
        C[(size_t)(row + r) * ldc + col] = acc[i][j][r];
    }
}

// ------- split-K reduce + fused dt_in bf16 cast -------
__global__ void splitk_reduce(const float* __restrict__ P, float* __restrict__ ssmp,
                              bf16* __restrict__ dtin) {
  int idx = blockIdx.x * 256 + threadIdx.x;  // t*160 + c
  float s = 0.f;
#pragma unroll
  for (int z = 0; z < KSP; z++) s += P[(size_t)z * L * 160 + idx];
  ssmp[idx] = s;
  int t = idx / 160, c = idx - t * 160;
  if (c < R) dtin[t * R + c] = __float2bfloat16(s);
}

// ---------------- causal depthwise conv (K=4) + bias + SiLU ----------------
__global__ void conv_silu(const bf16* __restrict__ projh,
                          const float* __restrict__ conv_w, const float* __restrict__ conv_b,
                          bf16* __restrict__ hs_b) {
  int idx = blockIdx.x * 256 + threadIdx.x;  // t*D + d
  int d = idx & (D - 1), t = idx >> 12;
  float acc = conv_b[d];
#pragma unroll
  for (int k = 0; k < KC; k++) {
    int tt = t + k - (KC - 1);
    if (tt >= 0) acc += __bfloat162float(projh[(size_t)tt * D + d]) * conv_w[k * D + d];
  }
  float s = acc / (1.f + __expf(-acc));
  hs_b[idx] = __float2bfloat16(s);
}

__device__ __forceinline__ float softplusf(float v) {
  return (v > 20.f) ? v : log1pf(__expf(v));
}

// ---------------- scan phase 1: per-chunk local scan ----------------
__global__ __launch_bounds__(256) void scan_phase1(
    const bf16* __restrict__ dtraw, const float* __restrict__ b_dt,
    const bf16* __restrict__ hs_b, const float* __restrict__ ssmp,
    const float* __restrict__ A_log,
    float* __restrict__ sdt_out, float* __restrict__ S_out) {
  const int d = blockIdx.x * 256 + threadIdx.x;
  const int c = blockIdx.y;
  float An[NS];
#pragma unroll
  for (int n = 0; n < NS; n++) An[n] = -__expf(A_log[d * NS + n]);
  const float bdt = b_dt[d];
  float s[NS];
#pragma unroll
  for (int n = 0; n < NS; n++) s[n] = 0.f;
  float sdt = 0.f;
  const int t0 = c * TCH;
#pragma unroll 2
  for (int t = t0; t < t0 + TCH; t++) {
    float dtv = softplusf(__bfloat162float(dtraw[(size_t)t * D + d]) + bdt);
    float hsv = __bfloat162float(hs_b[(size_t)t * D + d]);
    sdt += dtv;
    float u = dtv * hsv;
    const float* Bp = ssmp + (size_t)t * 160 + 128;
#pragma unroll
    for (int n = 0; n < NS; n++) {
      float dA = __expf(An[n] * dtv);
      s[n] = dA * s[n] + Bp[n] * u;
    }
  }
  sdt_out[(size_t)c * D + d] = sdt;
  float* Sp = S_out + ((size_t)c * D + d) * NS;
#pragma unroll
  for (int n = 0; n < NS; n += 4)
    *(floatx4*)(Sp + n) = *(floatx4*)(s + n);
}

// ---------------- scan phase 2: sequential combine over chunks (pipelined) ----------------
__global__ __launch_bounds__(256) void scan_phase2(
    const float* __restrict__ sdt, const float* __restrict__ S,
    const float* __restrict__ A_log, float* __restrict__ I) {
  int g = blockIdx.x * 256 + threadIdx.x;  // d*16 + n
  int d = g >> 4;
  float An = -__expf(A_log[g]);
  float cur = 0.f;
  float sdt_n = sdt[d];
  float S_n = S[g];
  for (int c = 0; c < CCH; c++) {
    float sdt_c = sdt_n, S_c = S_n;
    if (c + 1 < CCH) {
      sdt_n = sdt[(size_t)(c + 1) * D + d];
      S_n = S[(size_t)(c + 1) * D * NS + g];
    }
    I[(size_t)c * D * NS + g] = cur;
    cur = __expf(An * sdt_c) * cur + S_c;
  }
}

// ---------------- scan phase 3: seeded per-chunk scan + fused epilogue ----------------
__global__ __launch_bounds__(256) void scan_phase3(
    const bf16* __restrict__ dtraw, const float* __restrict__ b_dt,
    const bf16* __restrict__ hs_b, const float* __restrict__ ssmp,
    const bf16* __restrict__ gate_b, const float* __restrict__ A_log,
    const float* __restrict__ D_param, const float* __restrict__ I,
    bf16* __restrict__ y_b) {
  const int d = blockIdx.x * 256 + threadIdx.x;
  const int c = blockIdx.y;
  float An[NS];
#pragma unroll
  for (int n = 0; n < NS; n++) An[n] = -__expf(A_log[d * NS + n]);
  const float bdt = b_dt[d];
  const float Dp = D_param[d];
  float s[NS];
  const float* Ip = I + ((size_t)c * D + d) * NS;
#pragma unroll
  for (int n = 0; n < NS; n += 4)
    *(floatx4*)(s + n) = *(const floatx4*)(Ip + n);
  const int t0 = c * TCH;
#pragma unroll 2
  for (int t = t0; t < t0 + TCH; t++) {
    float dtv = softplusf(__bfloat162float(dtraw[(size_t)t * D + d]) + bdt);
    float hsv = __bfloat162float(hs_b[(size_t)t * D + d]);
    float u = dtv * hsv;
    const float* Bp = ssmp + (size_t)t * 160 + 128;
    const float* Cp = ssmp + (size_t)t * 160 + 144;
    float y = 0.f;
#pragma unroll
    for (int n = 0; n < NS; n++) {
      float dA = __expf(An[n] * dtv);
      s[n] = dA * s[n] + Bp[n] * u;
      y += s[n] * Cp[n];
    }
    float gv = __bfloat162float(gate_b[(size_t)t * D + d]);
    float yv = (y + hsv * Dp) * (gv / (1.f + __expf(-gv)));
    y_b[(size_t)t * D + d] = __float2bfloat16(yv);
  }
}

extern "C" void kernel_launch(void* const* d_in, const int* in_sizes, int n_in,
                              void* d_out, int out_size, void* d_ws, size_t ws_size,
                              hipStream_t stream) {
  const float* x      = (const float*)d_in[0];
  const float* W_in   = (const float*)d_in[1];
  const float* conv_w = (const float*)d_in[2];
  const float* conv_b = (const float*)d_in[3];
  const float* W_x    = (const float*)d_in[4];
  const float* W_dt   = (const float*)d_in[5];
  const float* b_dt   = (const float*)d_in[6];
  const float* A_log  = (const float*)d_in[7];
  const float* D_par  = (const float*)d_in[8];
  const float* W_out  = (const float*)d_in[9];
  float* outp = (float*)d_out;

  // ---- workspace layout with lifetime aliasing (peak ~192 MiB) ----
  char* ws = (char*)d_ws;
  size_t off = 0;
  auto alloc = [&](size_t bytes) {
    char* p = ws + off;
    off += (bytes + 255) & ~(size_t)255;
    return (void*)p;
  };
  // persistent region
  bf16*  gate_b  = (bf16*) alloc((size_t)L * D * 2);            // 16 MiB (alive till phase3)
  bf16*  hs_b    = (bf16*) alloc((size_t)L * D * 2);            // 16 MiB
  float* ssmp    = (float*)alloc((size_t)L * 160 * 4);          // 1.25 MiB
  bf16*  dtin_b  = (bf16*) alloc((size_t)L * R * 2);            // 0.5 MiB
  bf16*  dtbuf_b = (bf16*) alloc((size_t)L * D * 2);            // 16 MiB
  bf16*  y_b     = (bf16*) alloc((size_t)L * D * 2);            // 16 MiB
  bf16*  WoutT   = (bf16*) alloc((size_t)H * D * 2);            // 16 MiB (read at the end)
  float* sdt     = (float*)alloc((size_t)CCH * D * 4);          // 1 MiB
  float* Sbuf    = (float*)alloc((size_t)CCH * D * NS * 4);     // 16 MiB
  float* Ibuf    = (float*)alloc((size_t)CCH * D * NS * 4);     // 16 MiB
  // transient region: layout A (early pipeline) aliased with layout B (part2)
  size_t tbase = off;
  bf16*  x_b     = (bf16*) alloc((size_t)L * H * 2);            // 8 MiB   dead after proj
  bf16*  WinT    = (bf16*) alloc((size_t)2 * D * H * 2);        // 32 MiB  dead after proj
  bf16*  WxT     = (bf16*) alloc((size_t)160 * D * 2);          // 1.25 MiB dead after ssm_p
  bf16*  WdtT    = (bf16*) alloc((size_t)D * R * 2);            // 1 MiB   dead after dt GEMM
  bf16*  projh_b = (bf16*) alloc((size_t)L * D * 2);            // 16 MiB  dead after conv
  float* part    = (float*)alloc((size_t)KSP * L * 160 * 4);    // 20 MiB  dead after reduce
  bf16*  part2   = (bf16*)(ws + tbase);                         // 32 MiB (Z=4 bf16), aliases A

  cast_f2b<<<(L * H) / 256, 256, 0, stream>>>(x, x_b, L * H);

  dim3 tb(32, 8);
  transpose_cast<<<dim3((2 * D) / 32, H / 32), tb, 0, stream>>>(W_in, WinT, H, 2 * D);
  transpose_cast<<<dim3(H / 32, D / 32), tb, 0, stream>>>(W_out, WoutT, D, H);
  transpose_cast<<<dim3(160 / 32, D / 32), tb, 0, stream>>>(W_x, WxT, D, 160);
  transpose_cast<<<dim3(D / 32, R / 32), tb, 0, stream>>>(W_dt, WdtT, R, D);

  // proj = x @ W_in  [L, 2D]; hs-half -> bf16 projh_b, gate-half -> bf16 gate_b
  gemm256<2><<<dim3((2 * D) / 256, L / 256), 512, 0, stream>>>(
      x_b, H, WinT, H, projh_b, gate_b, D, H);
  // hs = silu(conv(projh)) -> bf16
  conv_silu<<<(L * D) / 256, 256, 0, stream>>>(projh_b, conv_w, conv_b, hs_b);
  // ssm_p = hs @ W_x  [L, 160] via split-K partials + reduce (fused dtin cast)
  gemm_splitk<<<dim3(2, L / 128, KSP), 256, 0, stream>>>(
      hs_b, D, WxT, D, part, 160, 160);
  splitk_reduce<<<(L * 160) / 256, 256, 0, stream>>>(part, ssmp, dtin_b);
  // dt_pre = dt_in @ W_dt  [L, D] bf16 (softplus folded into scan)
  gemm_async<1><<<dim3(D / 128, L / 128), 256, 0, stream>>>(
      dtin_b, R, WdtT, R, dtbuf_b, nullptr, D, R);

  // chunked scan
  scan_phase1<<<dim3(D / 256, CCH), 256, 0, stream>>>(
      dtbuf_b, b_dt, hs_b, ssmp, A_log, sdt, Sbuf);
  scan_phase2<<<(D * NS) / 256, 256, 0, stream>>>(sdt, Sbuf, A_log, Ibuf);
  scan_phase3<<<dim3(D / 256, CCH), 256, 0, stream>>>(
      dtbuf_b, b_dt, hs_b, ssmp, gate_b, A_log, D_par, Ibuf, y_b);

  // out = y @ W_out  [L, H]: Z=4 split-K, 256x256 tiles, bf16 partials + reduce
  gemm256<3><<<dim3(H / 256, L / 256, ZOUT), 512, 0, stream>>>(
      y_b, D, WoutT, D, part2, nullptr, H, KOUT);
  out_reduce<<<(L * H) / (256 * 8), 256, 0, stream>>>((const unsigned short*)part2, outp);
}

// Round 4
// 472.487 us; speedup vs baseline: 1.0128x; 1.0128x over previous
//
#include <hip/hip_runtime.h>
#include <hip/hip_bf16.h>

typedef short short8 __attribute__((ext_vector_type(8)));
typedef float floatx4 __attribute__((ext_vector_type(4)));
using bf16 = __hip_bfloat16;

static constexpr int L = 2048, H = 2048, D = 4096, NS = 16, R = 128, KC = 4;
static constexpr int CCH = 64, TCH = L / CCH;        // 64 chunks x 32 steps
static constexpr int KSP = 16, KCHUNK = 4096 / KSP;  // split-K for ssm_p
static constexpr int ZOUT = 4, KOUT = 4096 / ZOUT;   // split-K for out GEMM

__device__ __forceinline__ void g2lds16(const void* g, void* l) {
  __builtin_amdgcn_global_load_lds((const __attribute__((address_space(1))) unsigned int*)g,
                                   (__attribute__((address_space(3))) unsigned int*)l,
                                   16, 0, 0);
}

// ---------------- elementwise fp32 -> bf16 cast ----------------
__global__ void cast_f2b(const float* __restrict__ in, bf16* __restrict__ out, int n) {
  int i = blockIdx.x * 256 + threadIdx.x;
  if (i < n) out[i] = __float2bfloat16(in[i]);
}

// ------------- weight transpose+cast (fp32 [Rr,Cc] -> bf16 [Cc,Rr]) -------------
__global__ void transpose_cast(const float* __restrict__ in, bf16* __restrict__ out,
                               int Rr, int Cc) {
  __shared__ float tile[32][33];
  int c0 = blockIdx.x * 32, r0 = blockIdx.y * 32;
  int tx = threadIdx.x, ty = threadIdx.y;  // 32 x 8
#pragma unroll
  for (int i = 0; i < 32; i += 8)
    tile[ty + i][tx] = in[(size_t)(r0 + ty + i) * Cc + (c0 + tx)];
  __syncthreads();
#pragma unroll
  for (int i = 0; i < 32; i += 8)
    out[(size_t)(c0 + ty + i) * Rr + (r0 + tx)] = __float2bfloat16(tile[tx][ty + i]);
}

// ==================== 256x256 4-barrier MFMA GEMM (T1+T2+T4+T5) ====================
// C[M,N] = A[M,K]*Bt[N,K]^T, K multiple of 128 (NT even), M,N multiples of 256.
// MODE 2: proj split — block col selects Cb (hs) or Cb2 (gate), both bf16 [L,D].
// MODE 3: split-K bf16 partials: kbeg = blockIdx.z*K, C = Cb + blockIdx.z*L*ldc.
//
// LDS: per matrix 4 panels of [256 rows][32 k-cols] bf16 (16 KiB each) = 64 KiB;
// panel (t&1)*2 + khalf. Total 128 KiB -> 1 block/CU, 8 waves.
// st_16x32 swizzle: physical 16B chunk = logical chunk ^ (((row>>3)&1)<<1),
// applied on the global SOURCE at staging (global_load_lds writes linearly)
// and on the ds_read address at consume.
//   staging lane covers row (lane>>2) -> row bit 3 = lane bit 5;
//   read lane covers row lr=(lane&15) -> row bit 3 = lane bit 3.
//
// Scheduling (R4): NO forced lgkmcnt(0)+sched_barrier before MFMA — the compiler
// emits fine-grained counted lgkmcnt per MFMA operand, overlapping the block-wide
// LDS drain with MFMA issue. One barrier per sub-phase (4/K-tile). Memory safety:
//  - each stage target's previous readers are >=1 end-barrier behind;
//  - ds_read vs in-flight stage ordering pinned by the vmcnt asm (memory clobber);
//  - lgkmcnt(0) at p1-end / p3-end (pre-overwrite points) pins read retirement.
// Counted vmcnt (never 0 in steady state):
//   p1-end  vmcnt(8): drains (t).kh1   — issued 6 sub-phases earlier
//   p3-end  vmcnt(8): drains (t+1).kh0 — issued 6 sub-phases earlier
template <int MODE>
__global__ __launch_bounds__(512, 2) void gemm256(
    const bf16* __restrict__ A, int lda,
    const bf16* __restrict__ Bt, int ldb,
    bf16* __restrict__ Cb, bf16* __restrict__ Cb2, int ldc, int K) {
  __shared__ short As[4 * 8192];
  __shared__ short Bs[4 * 8192];

  // ---- XCD-aware rectangular tile map (hw XCD = linear id % 8 heuristic) ----
  // Per-XCD rectangle rn x rm tiles (4 XCD-cols x 2 XCD-rows); bijective for
  // gx%4==0 && gy%2==0 (proj 32x8, out 8x8).
  const int gx = gridDim.x, gy = gridDim.y;
  const int orig = blockIdx.y * gx + blockIdx.x;
  const int xcd = orig & 7;
  const int rr = orig >> 3;
  const int rn = gx >> 2, rm = gy >> 1;
  const int tn = (xcd & 3) * rn + (rr % rn);
  const int tm = (xcd >> 2) * rm + (rr / rn);
  const int n0 = tn * 256, m0 = tm * 256;
  const int kbeg = (MODE == 3) ? blockIdx.z * K : 0;
  const int NT = K >> 6;  // K-tiles of 64

  const int tid = threadIdx.x;
  const int lane = tid & 63;
  const int w = tid >> 6;
  const int wm2 = w >> 2, wn4 = w & 3;      // wave tile: 128 rows x 64 cols
  const int lr = lane & 15, kq = lane >> 4;
  // ---- read-side swizzle: row bit 3 = lane bit 3 ----
  const int swzr = ((lane >> 3) & 1) << 1;
  // ds_read offsets (shorts): row*32 + swizzled 16B chunk
  const int ardo = (wm2 * 128 + lr) * 32 + (kq ^ swzr) * 8;
  const int brdo = (wn4 * 64 + lr) * 32 + (kq ^ swzr) * 8;
  // ---- staging: per-lane row (0..127 per dwordx4 instr); row bit 3 = lane bit 5 ----
  const int srow = w * 16 + (lane >> 2);
  const int swzs = ((lane >> 5) & 1) << 1;
  const int scol = ((lane & 3) ^ swzs) * 8;

  floatx4 acc[8][4];
#pragma unroll
  for (int i = 0; i < 8; i++)
#pragma unroll
    for (int j = 0; j < 4; j++)
#pragma unroll
      for (int r = 0; r < 4; r++) acc[i][j][r] = 0.f;

  // stage one half-tile (one khalf panel): 2 x global_load_lds dwordx4
  auto stageA = [&](short* pan, int kc) {
    const bf16* g = A + (size_t)(m0 + srow) * lda + (kbeg + kc + scol);
    g2lds16(g, pan + w * 512);
    g2lds16(g + (size_t)128 * lda, pan + 4096 + w * 512);
  };
  auto stageB = [&](short* pan, int kc) {
    const bf16* g = Bt + (size_t)(n0 + srow) * ldb + (kbeg + kc + scol);
    g2lds16(g, pan + w * 512);
    g2lds16(g + (size_t)128 * ldb, pan + 4096 + w * 512);
  };

#define LDA4(pan, base)                                               \
  _Pragma("unroll") for (int ii = 0; ii < 4; ii++)                    \
      af[ii] = *(const short8*)((pan) + ardo + ((base) + ii) * 512);
#define LDB4(pan)                                                     \
  _Pragma("unroll") for (int jj = 0; jj < 4; jj++)                    \
      bfr[jj] = *(const short8*)((pan) + brdo + jj * 512);
#define MFMA4(base)                                                   \
  _Pragma("unroll") for (int ii = 0; ii < 4; ii++)                    \
      _Pragma("unroll") for (int jj = 0; jj < 4; jj++)                \
          acc[(base) + ii][jj] = __builtin_amdgcn_mfma_f32_16x16x32_bf16( \
              af[ii], bfr[jj], acc[(base) + ii][jj], 0, 0, 0);
#define LGK0() asm volatile("s_waitcnt lgkmcnt(0)" ::: "memory");
#define VMW(n) asm volatile("s_waitcnt vmcnt(" #n ")" ::: "memory");
#define BAR() __builtin_amdgcn_s_barrier();

  // ---- prologue: halves {t0.kh0.A, t0.kh0.B, t0.kh1.A, t0.kh1.B, t1.kh0.A, t1.kh0.B}
  stageA(As + 0 * 8192, 0);
  stageB(Bs + 0 * 8192, 0);
  stageA(As + 1 * 8192, 32);
  stageB(Bs + 1 * 8192, 32);
  stageA(As + 2 * 8192, 64);
  stageB(Bs + 2 * 8192, 64);
  VMW(8);  // t0.kh0 resident (t0.kh1 + t1.kh0 stay in flight)
  BAR();

// ---- one K-tile: 4 sub-phases of (khalf, m-half); stages per phase:
//   p0: A.kh1(t+1)  p1: B.kh1(t+1)  p2: A.kh0(t+2)  p3: B.kh0(t+2)
#define GTILE(t, par)                                                      \
  {                                                                        \
    short* Ak0 = As + (par) * 16384;                                       \
    short* Bk0 = Bs + (par) * 16384;                                       \
    short* Ak1 = Ak0 + 8192;                                               \
    short* Bk1 = Bk0 + 8192;                                               \
    short* An1 = As + (1 - (par)) * 16384 + 8192;                          \
    short* Bn1 = Bs + (1 - (par)) * 16384 + 8192;                          \
    short8 af[4], bfr[4];                                                  \
    /* p0: kh0, m-frags 0..3 */                                            \
    LDB4(Bk0); LDA4(Ak0, 0);                                               \
    if ((t) + 1 < NT) stageA(An1, ((t) + 1) * 64 + 32);                    \
    __builtin_amdgcn_s_setprio(1); MFMA4(0); __builtin_amdgcn_s_setprio(0);\
    BAR();                                                                 \
    /* p1: kh0, m-frags 4..7 (bfr reused) */                               \
    LDA4(Ak0, 4);                                                          \
    if ((t) + 1 < NT) stageB(Bn1, ((t) + 1) * 64 + 32);                    \
    __builtin_amdgcn_s_setprio(1); MFMA4(4); __builtin_amdgcn_s_setprio(0);\
    LGK0();                                                                \
    if ((t) < NT - 1) { VMW(8); } else { VMW(0); }  /* drain (t).kh1 */    \
    BAR();                                                                 \
    /* p2: kh1, m-frags 0..3 */                                            \
    LDB4(Bk1); LDA4(Ak1, 0);                                               \
    if ((t) + 2 < NT) stageA(Ak0, ((t) + 2) * 64);                         \
    __builtin_amdgcn_s_setprio(1); MFMA4(0); __builtin_amdgcn_s_setprio(0);\
    BAR();                                                                 \
    /* p3: kh1, m-frags 4..7 (bfr reused) */                               \
    LDA4(Ak1, 4);                                                          \
    if ((t) + 2 < NT) stageB(Bk0, ((t) + 2) * 64);                         \
    __builtin_amdgcn_s_setprio(1); MFMA4(4); __builtin_amdgcn_s_setprio(0);\
    LGK0();                                                                \
    /* drain (t+1).kh0 */                                                  \
    if ((t) < NT - 2) { VMW(8); }                                          \
    else if ((t) == NT - 2) { VMW(4); }                                    \
    else { VMW(0); }                                                       \
    BAR();                                                                 \
  }

  for (int t = 0; t < NT; t += 2) {
    GTILE(t, 0);
    GTILE(t + 1, 1);
  }
#undef GTILE
#undef BAR
#undef VMW
#undef LGK0
#undef MFMA4
#undef LDB4
#undef LDA4

  // ---- epilogue ----
  bf16* base = Cb;
  int coff = 0, ld = ldc;
  if (MODE == 2) {
    if (n0 >= D) { base = Cb2; coff = D; }
    ld = D;
  }
  if (MODE == 3) base = Cb + (size_t)blockIdx.z * L * ldc;
  const int rb = kq * 4;  // C/D: col = lane&15, row = (lane>>4)*4 + reg
#pragma unroll
  for (int i = 0; i < 8; i++)
#pragma unroll
    for (int j = 0; j < 4; j++) {
      int col = n0 + wn4 * 64 + j * 16 + lr - coff;
      int row = m0 + wm2 * 128 + i * 16 + rb;
#pragma unroll
      for (int r = 0; r < 4; r++)
        base[(size_t)(row + r) * ld + col] = __float2bfloat16(acc[i][j][r]);
    }
}

// ------- dense bf16 MFMA GEMM (old 128x128 structure) — kept for the small dt GEMM -------
template <int MODE>
__global__ __launch_bounds__(256) void gemm_async(
    const bf16* __restrict__ A, int lda,
    const bf16* __restrict__ Bt, int ldb,
    bf16* __restrict__ Cb, bf16* __restrict__ Cb2, int ldc, int K) {
  __shared__ short As[2 * 128 * 32];
  __shared__ short Bs[2 * 128 * 32];
  const int m0 = blockIdx.y * 128, n0 = blockIdx.x * 128;
  const int kbeg = (MODE == 3) ? blockIdx.z * K : 0;
  const int tid = threadIdx.x;
  const int lane = tid & 63;
  const int wave = tid >> 6;
  const int wm = (wave >> 1) * 64, wn = (wave & 1) * 64;
  const int lr = lane & 15, kq = lane >> 4;
  const int sr = lane >> 2, sc = (lane & 3) * 8;

  const bf16* Ab = A + (size_t)(m0 + wave * 16 + sr) * lda + sc;
  const bf16* Bb = Bt + (size_t)(n0 + wave * 16 + sr) * ldb + sc;
  short* Asw = &As[wave * 16 * 32];
  short* Bsw = &Bs[wave * 16 * 32];

  floatx4 acc[4][4];
#pragma unroll
  for (int i = 0; i < 4; i++)
#pragma unroll
    for (int j = 0; j < 4; j++)
#pragma unroll
      for (int r = 0; r < 4; r++) acc[i][j][r] = 0.f;

  for (int k0 = kbeg; k0 < kbeg + K; k0 += 64) {
    __syncthreads();
#pragma unroll
    for (int h = 0; h < 2; h++) {
      int kk = k0 + h * 32;
#pragma unroll
      for (int j = 0; j < 2; j++) {
        g2lds16(Ab + (size_t)j * 64 * lda + kk, Asw + h * 4096 + j * 64 * 32);
        g2lds16(Bb + (size_t)j * 64 * ldb + kk, Bsw + h * 4096 + j * 64 * 32);
      }
    }
    __syncthreads();
#pragma unroll
    for (int h = 0; h < 2; h++) {
      short8 af[4], bfr[4];
#pragma unroll
      for (int i = 0; i < 4; i++)
        af[i] = *(const short8*)(&As[h * 4096 + (wm + i * 16 + lr) * 32 + kq * 8]);
#pragma unroll
      for (int j = 0; j < 4; j++)
        bfr[j] = *(const short8*)(&Bs[h * 4096 + (wn + j * 16 + lr) * 32 + kq * 8]);
#pragma unroll
      for (int i = 0; i < 4; i++)
#pragma unroll
        for (int j = 0; j < 4; j++)
          acc[i][j] = __builtin_amdgcn_mfma_f32_16x16x32_bf16(af[i], bfr[j], acc[i][j], 0, 0, 0);
    }
  }

  bf16* base = Cb;
  int coff = 0, ld = ldc;
  if (MODE == 2) {
    if (n0 >= D) { base = Cb2; coff = D; }
    ld = D;
  }
  if (MODE == 3) base = Cb + (size_t)blockIdx.z * L * ldc;
  const int rb = kq * 4;
#pragma unroll
  for (int i = 0; i < 4; i++)
#pragma unroll
    for (int j = 0; j < 4; j++) {
      int col = n0 + wn + j * 16 + lr - coff;
      int row = m0 + wm + i * 16 + rb;
#pragma unroll
      for (int r = 0; r < 4; r++)
        base[(size_t)(row + r) * ld + col] = __float2bfloat16(acc[i][j][r]);
    }
}

// ------- out split-K reduce: bf16 partials -> fp32, 8 elems/thread -------
__global__ void out_reduce(const unsigned short* __restrict__ P, float* __restrict__ out) {
  int i = blockIdx.x * 256 + threadIdx.x;
  const size_t LH = (size_t)L * H;
  float acc[8];
#pragma unroll
  for (int e = 0; e < 8; e++) acc[e] = 0.f;
#pragma unroll
  for (int z = 0; z < ZOUT; z++) {
    short8 v = *(const short8*)(P + z * LH + (size_t)i * 8);
#pragma unroll
    for (int e = 0; e < 8; e++)
      acc[e] += __uint_as_float(((unsigned)(unsigned short)v[e]) << 16);
  }
#pragma unroll
  for (int q = 0; q < 2; q++) {
    floatx4 o;
#pragma unroll
    for (int r = 0; r < 4; r++) o[r] = acc[q * 4 + r];
    *(floatx4*)(out + (size_t)i * 8 + q * 4) = o;
  }
}

// ------- split-K guarded GEMM for ssm_p: partial[z][M][N] over K-chunk -------
__global__ __launch_bounds__(256) void gemm_splitk(
    const bf16* __restrict__ A, int lda,
    const bf16* __restrict__ Bt, int ldb,
    float* __restrict__ P, int ldc, int N) {
  __shared__ short As[128 * 40];
  __shared__ short Bs[128 * 40];
  const int m0 = blockIdx.y * 128, n0 = blockIdx.x * 128;
  const int kbeg = blockIdx.z * KCHUNK;
  float* C = P + (size_t)blockIdx.z * L * ldc;
  const int tid = threadIdx.x;
  const int lane = tid & 63;
  const int wave = tid >> 6;
  const int wm = (wave >> 1) * 64, wn = (wave & 1) * 64;
  const int lr = lane & 15, kq = lane >> 4;
  const int srow = tid >> 2, scol = (tid & 3) * 8;

  floatx4 acc[4][4];
#pragma unroll
  for (int i = 0; i < 4; i++)
#pragma unroll
    for (int j = 0; j < 4; j++)
#pragma unroll
      for (int r = 0; r < 4; r++) acc[i][j][r] = 0.f;

  for (int k0 = kbeg; k0 < kbeg + KCHUNK; k0 += 32) {
    __syncthreads();
#pragma unroll
    for (int h = 0; h < 2; h++) {
      int r = srow + h * 64;
      short8 va = *(const short8*)((const short*)A + (size_t)(m0 + r) * lda + k0 + scol);
      *(short8*)(&As[r * 40 + scol]) = va;
    }
#pragma unroll
    for (int h = 0; h < 2; h++) {
      int r = srow + h * 64;
      short8 vb;
      if ((n0 + r) < N) {
        vb = *(const short8*)((const short*)Bt + (size_t)(n0 + r) * ldb + k0 + scol);
      } else {
#pragma unroll
        for (int q = 0; q < 8; q++) vb[q] = 0;
      }
      *(short8*)(&Bs[r * 40 + scol]) = vb;
    }
    __syncthreads();
    short8 af[4], bfr[4];
#pragma unroll
    for (int i = 0; i < 4; i++)
      af[i] = *(const short8*)(&As[(wm + i * 16 + lr) * 40 + kq * 8]);
#pragma unroll
    for (int j = 0; j < 4; j++)
      bfr[j] = *(const short8*)(&Bs[(wn + j * 16 + lr) * 40 + kq * 8]);
#pragma unroll
    for (int i = 0; i < 4; i++)
#pragma unroll
      for (int j = 0; j < 4; j++)
        acc[i][j] = __builtin_amdgcn_mfma_f32_16x16x32_bf16(af[i], bfr[j], acc[i][j], 0, 0, 0);
  }

  const int rb = kq * 4;
#pragma unroll
  for (int i = 0; i < 4; i++)
#pragma unroll
    for (int j = 0; j < 4; j++) {
      int col = n0 + wn + j * 16 + lr;
      if (col >= N) continue;
      int row = m0 + wm + i * 16 + rb;
#pragma unroll
      for (int r = 0; r < 4; r++)
        C[(size_t)(row + r) * ldc + col] = acc[i][j][r];
    }
}

// ------- split-K reduce + fused dt_in bf16 cast -------
__global__ void splitk_reduce(const float* __restrict__ P, float* __restrict__ ssmp,
                              bf16* __restrict__ dtin) {
  int idx = blockIdx.x * 256 + threadIdx.x;  // t*160 + c
  float s = 0.f;
#pragma unroll
  for (int z = 0; z < KSP; z++) s += P[(size_t)z * L * 160 + idx];
  ssmp[idx] = s;
  int t = idx / 160, c = idx - t * 160;
  if (c < R) dtin[t * R + c] = __float2bfloat16(s);
}

// ---------------- causal depthwise conv (K=4) + bias + SiLU ----------------
__global__ void conv_silu(const bf16* __restrict__ projh,
                          const float* __restrict__ conv_w, const float* __restrict__ conv_b,
                          bf16* __restrict__ hs_b) {
  int idx = blockIdx.x * 256 + threadIdx.x;  // t*D + d
  int d = idx & (D - 1), t = idx >> 12;
  float acc = conv_b[d];
#pragma unroll
  for (int k = 0; k < KC; k++) {
    int tt = t + k - (KC - 1);
    if (tt >= 0) acc += __bfloat162float(projh[(size_t)tt * D + d]) * conv_w[k * D + d];
  }
  float s = acc / (1.f + __expf(-acc));
  hs_b[idx] = __float2bfloat16(s);
}

__device__ __forceinline__ float softplusf(float v) {
  return (v > 20.f) ? v : log1pf(__expf(v));
}

// ---------------- scan phase 1: per-chunk local scan ----------------
__global__ __launch_bounds__(256) void scan_phase1(
    const bf16* __restrict__ dtraw, const float* __restrict__ b_dt,
    const bf16* __restrict__ hs_b, const float* __restrict__ ssmp,
    const float* __restrict__ A_log,
    float* __restrict__ sdt_out, float* __restrict__ S_out) {
  const int d = blockIdx.x * 256 + threadIdx.x;
  const int c = blockIdx.y;
  float An[NS];
#pragma unroll
  for (int n = 0; n < NS; n++) An[n] = -__expf(A_log[d * NS + n]);
  const float bdt = b_dt[d];
  float s[NS];
#pragma unroll
  for (int n = 0; n < NS; n++) s[n] = 0.f;
  float sdt = 0.f;
  const int t0 = c * TCH;
#pragma unroll 2
  for (int t = t0; t < t0 + TCH; t++) {
    float dtv = softplusf(__bfloat162float(dtraw[(size_t)t * D + d]) + bdt);
    float hsv = __bfloat162float(hs_b[(size_t)t * D + d]);
    sdt += dtv;
    float u = dtv * hsv;
    const float* Bp = ssmp + (size_t)t * 160 + 128;
#pragma unroll
    for (int n = 0; n < NS; n++) {
      float dA = __expf(An[n] * dtv);
      s[n] = dA * s[n] + Bp[n] * u;
    }
  }
  sdt_out[(size_t)c * D + d] = sdt;
  float* Sp = S_out + ((size_t)c * D + d) * NS;
#pragma unroll
  for (int n = 0; n < NS; n += 4)
    *(floatx4*)(Sp + n) = *(floatx4*)(s + n);
}

// ---------------- scan phase 2: sequential combine over chunks (pipelined) ----------------
__global__ __launch_bounds__(256) void scan_phase2(
    const float* __restrict__ sdt, const float* __restrict__ S,
    const float* __restrict__ A_log, float* __restrict__ I) {
  int g = blockIdx.x * 256 + threadIdx.x;  // d*16 + n
  int d = g >> 4;
  float An = -__expf(A_log[g]);
  float cur = 0.f;
  float sdt_n = sdt[d];
  float S_n = S[g];
  for (int c = 0; c < CCH; c++) {
    float sdt_c = sdt_n, S_c = S_n;
    if (c + 1 < CCH) {
      sdt_n = sdt[(size_t)(c + 1) * D + d];
      S_n = S[(size_t)(c + 1) * D * NS + g];
    }
    I[(size_t)c * D * NS + g] = cur;
    cur = __expf(An * sdt_c) * cur + S_c;
  }
}

// ---------------- scan phase 3: seeded per-chunk scan + fused epilogue ----------------
__global__ __launch_bounds__(256) void scan_phase3(
    const bf16* __restrict__ dtraw, const float* __restrict__ b_dt,
    const bf16* __restrict__ hs_b, const float* __restrict__ ssmp,
    const bf16* __restrict__ gate_b, const float* __restrict__ A_log,
    const float* __restrict__ D_param, const float* __restrict__ I,
    bf16* __restrict__ y_b) {
  const int d = blockIdx.x * 256 + threadIdx.x;
  const int c = blockIdx.y;
  float An[NS];
#pragma unroll
  for (int n = 0; n < NS; n++) An[n] = -__expf(A_log[d * NS + n]);
  const float bdt = b_dt[d];
  const float Dp = D_param[d];
  float s[NS];
  const float* Ip = I + ((size_t)c * D + d) * NS;
#pragma unroll
  for (int n = 0; n < NS; n += 4)
    *(floatx4*)(s + n) = *(const floatx4*)(Ip + n);
  const int t0 = c * TCH;
#pragma unroll 2
  for (int t = t0; t < t0 + TCH; t++) {
    float dtv = softplusf(__bfloat162float(dtraw[(size_t)t * D + d]) + bdt);
    float hsv = __bfloat162float(hs_b[(size_t)t * D + d]);
    float u = dtv * hsv;
    const float* Bp = ssmp + (size_t)t * 160 + 128;
    const float* Cp = ssmp + (size_t)t * 160 + 144;
    float y = 0.f;
#pragma unroll
    for (int n = 0; n < NS; n++) {
      float dA = __expf(An[n] * dtv);
      s[n] = dA * s[n] + Bp[n] * u;
      y += s[n] * Cp[n];
    }
    float gv = __bfloat162float(gate_b[(size_t)t * D + d]);
    float yv = (y + hsv * Dp) * (gv / (1.f + __expf(-gv)));
    y_b[(size_t)t * D + d] = __float2bfloat16(yv);
  }
}

extern "C" void kernel_launch(void* const* d_in, const int* in_sizes, int n_in,
                              void* d_out, int out_size, void* d_ws, size_t ws_size,
                              hipStream_t stream) {
  const float* x      = (const float*)d_in[0];
  const float* W_in   = (const float*)d_in[1];
  const float* conv_w = (const float*)d_in[2];
  const float* conv_b = (const float*)d_in[3];
  const float* W_x    = (const float*)d_in[4];
  const float* W_dt   = (const float*)d_in[5];
  const float* b_dt   = (const float*)d_in[6];
  const float* A_log  = (const float*)d_in[7];
  const float* D_par  = (const float*)d_in[8];
  const float* W_out  = (const float*)d_in[9];
  float* outp = (float*)d_out;

  // ---- workspace layout with lifetime aliasing (peak ~192 MiB) ----
  char* ws = (char*)d_ws;
  size_t off = 0;
  auto alloc = [&](size_t bytes) {
    char* p = ws + off;
    off += (bytes + 255) & ~(size_t)255;
    return (void*)p;
  };
  // persistent region
  bf16*  gate_b  = (bf16*) alloc((size_t)L * D * 2);            // 16 MiB (alive till phase3)
  bf16*  hs_b    = (bf16*) alloc((size_t)L * D * 2);            // 16 MiB
  float* ssmp    = (float*)alloc((size_t)L * 160 * 4);          // 1.25 MiB
  bf16*  dtin_b  = (bf16*) alloc((size_t)L * R * 2);            // 0.5 MiB
  bf16*  dtbuf_b = (bf16*) alloc((size_t)L * D * 2);            // 16 MiB
  bf16*  y_b     = (bf16*) alloc((size_t)L * D * 2);            // 16 MiB
  bf16*  WoutT   = (bf16*) alloc((size_t)H * D * 2);            // 16 MiB (read at the end)
  float* sdt     = (float*)alloc((size_t)CCH * D * 4);          // 1 MiB
  float* Sbuf    = (float*)alloc((size_t)CCH * D * NS * 4);     // 16 MiB
  float* Ibuf    = (float*)alloc((size_t)CCH * D * NS * 4);     // 16 MiB
  // transient region: layout A (early pipeline) aliased with layout B (part2)
  size_t tbase = off;
  bf16*  x_b     = (bf16*) alloc((size_t)L * H * 2);            // 8 MiB   dead after proj
  bf16*  WinT    = (bf16*) alloc((size_t)2 * D * H * 2);        // 32 MiB  dead after proj
  bf16*  WxT     = (bf16*) alloc((size_t)160 * D * 2);          // 1.25 MiB dead after ssm_p
  bf16*  WdtT    = (bf16*) alloc((size_t)D * R * 2);            // 1 MiB   dead after dt GEMM
  bf16*  projh_b = (bf16*) alloc((size_t)L * D * 2);            // 16 MiB  dead after conv
  float* part    = (float*)alloc((size_t)KSP * L * 160 * 4);    // 20 MiB  dead after reduce
  bf16*  part2   = (bf16*)(ws + tbase);                         // 32 MiB (Z=4 bf16), aliases A

  cast_f2b<<<(L * H) / 256, 256, 0, stream>>>(x, x_b, L * H);

  dim3 tb(32, 8);
  transpose_cast<<<dim3((2 * D) / 32, H / 32), tb, 0, stream>>>(W_in, WinT, H, 2 * D);
  transpose_cast<<<dim3(H / 32, D / 32), tb, 0, stream>>>(W_out, WoutT, D, H);
  transpose_cast<<<dim3(160 / 32, D / 32), tb, 0, stream>>>(W_x, WxT, D, 160);
  transpose_cast<<<dim3(D / 32, R / 32), tb, 0, stream>>>(W_dt, WdtT, R, D);

  // proj = x @ W_in  [L, 2D]; hs-half -> bf16 projh_b, gate-half -> bf16 gate_b
  gemm256<2><<<dim3((2 * D) / 256, L / 256), 512, 0, stream>>>(
      x_b, H, WinT, H, projh_b, gate_b, D, H);
  // hs = silu(conv(projh)) -> bf16
  conv_silu<<<(L * D) / 256, 256, 0, stream>>>(projh_b, conv_w, conv_b, hs_b);
  // ssm_p = hs @ W_x  [L, 160] via split-K partials + reduce (fused dtin cast)
  gemm_splitk<<<dim3(2, L / 128, KSP), 256, 0, stream>>>(
      hs_b, D, WxT, D, part, 160, 160);
  splitk_reduce<<<(L * 160) / 256, 256, 0, stream>>>(part, ssmp, dtin_b);
  // dt_pre = dt_in @ W_dt  [L, D] bf16 (softplus folded into scan)
  gemm_async<1><<<dim3(D / 128, L / 128), 256, 0, stream>>>(
      dtin_b, R, WdtT, R, dtbuf_b, nullptr, D, R);

  // chunked scan
  scan_phase1<<<dim3(D / 256, CCH), 256, 0, stream>>>(
      dtbuf_b, b_dt, hs_b, ssmp, A_log, sdt, Sbuf);
  scan_phase2<<<(D * NS) / 256, 256, 0, stream>>>(sdt, Sbuf, A_log, Ibuf);
  scan_phase3<<<dim3(D / 256, CCH), 256, 0, stream>>>(
      dtbuf_b, b_dt, hs_b, ssmp, gate_b, A_log, D_par, Ibuf, y_b);

  // out = y @ W_out  [L, H]: Z=4 split-K, 256x256 tiles, bf16 partials + reduce
  gemm256<3><<<dim3(H / 256, L / 256, ZOUT), 512, 0, stream>>>(
      y_b, D, WoutT, D, part2, nullptr, H, KOUT);
  out_reduce<<<(L * H) / (256 * 8), 256, 0, stream>>>((const unsigned short*)part2, outp);
}